// Round 2
// baseline (429.437 us; speedup 1.0000x reference)
//
#include <hip/hip_runtime.h>

#define NB 32
#define NS 2048
#define ND 512
#define NA 64
#define NE 64

typedef __bf16 bf16x8 __attribute__((ext_vector_type(8)));
typedef float f32x4 __attribute__((ext_vector_type(4)));

__device__ __forceinline__ unsigned short f2bf(float f) {
    union { float f; unsigned u; } v; v.f = f;
    unsigned r = (v.u + 0x7fffu + ((v.u >> 16) & 1u)) >> 16;
    return (unsigned short)r;
}
__device__ __forceinline__ unsigned pk(float a, float b) {
    return (unsigned)f2bf(a) | ((unsigned)f2bf(b) << 16);
}
__device__ __forceinline__ float bflo(unsigned u) {
    return __builtin_bit_cast(float, u << 16);
}
__device__ __forceinline__ float bfhi(unsigned u) {
    return __builtin_bit_cast(float, u & 0xffff0000u);
}

// ---------------------------------------------------------------------------
// Kernel 1a: hypernet big GEMMs  emb[32,64] @ W[64,32768] -> bf16 frags.
// Down frags (RAW, folded later by hyper_c): [b][nblk(4)][kc(16)][lane(64)][8]
// Up frags: [b][nblk(32)][kch(2)][lane(64)][8]
// ---------------------------------------------------------------------------
__global__ __launch_bounds__(256) void hyper_pack(
    const float* __restrict__ emb,
    const float* __restrict__ dwW, const float* __restrict__ dwb,
    const float* __restrict__ uwW, const float* __restrict__ uwb,
    unsigned short* __restrict__ wdfrag, unsigned short* __restrict__ wufrag) {
    __shared__ float Wt[64][256];
    __shared__ float embs[NB * NE];
    const int tid = threadIdx.x;
    const int bx = blockIdx.x;
    const int mat = bx >> 7;
    const int chunk = bx & 127;
    const int base = chunk * 256;
    const float* W = mat ? uwW : dwW;
    const float* bias = mat ? uwb : dwb;

    for (int i = tid; i < NB * NE; i += 256) embs[i] = emb[i];
    for (int i = tid; i < 64 * 64; i += 256) {
        int k = i >> 6, c = (i & 63) << 2;
        *(float4*)&Wt[k][c] = *(const float4*)&W[(size_t)k * 32768 + base + c];
    }
    __syncthreads();

    const int col = base + tid;
    const float bv = bias[col];
    float acc[NB];
#pragma unroll
    for (int b = 0; b < NB; ++b) acc[b] = bv;

    for (int k0 = 0; k0 < 64; k0 += 4) {
        float w0 = Wt[k0][tid], w1 = Wt[k0 + 1][tid];
        float w2 = Wt[k0 + 2][tid], w3 = Wt[k0 + 3][tid];
#pragma unroll
        for (int b = 0; b < NB; ++b) {
            float4 e = *(const float4*)&embs[b * 64 + k0];
            acc[b] = fmaf(e.x, w0, acc[b]);
            acc[b] = fmaf(e.y, w1, acc[b]);
            acc[b] = fmaf(e.z, w2, acc[b]);
            acc[b] = fmaf(e.w, w3, acc[b]);
        }
    }

    if (mat == 0) {
        int a = col >> 9, d = col & 511;
        size_t idx0 = ((size_t)((a >> 4) * 16 + (d >> 5)) * 64 +
                       (((d & 31) >> 3) * 16 + (a & 15))) * 8 + (d & 7);
#pragma unroll
        for (int b = 0; b < NB; ++b) wdfrag[idx0 + (size_t)b * 32768] = f2bf(acc[b]);
    } else {
        int d = col >> 6, a = col & 63;
        size_t idx0 = ((size_t)((d >> 4) * 2 + (a >> 5)) * 64 +
                       (((a & 31) >> 3) * 16 + (d & 15))) * 8 + (a & 7);
#pragma unroll
        for (int b = 0; b < NB; ++b) wufrag[idx0 + (size_t)b * 32768] = f2bf(acc[b]);
    }
}

// ---------------------------------------------------------------------------
// Kernel 1b: the six small per-sample vectors, per b:
// [pre_w 512][pre_b 512][post_w 512][post_b 512][b_up 512][b_down 64] = 2624
// ---------------------------------------------------------------------------
__global__ __launch_bounds__(256) void hyper_vec(
    const float* __restrict__ emb,
    const float* __restrict__ pwW, const float* __restrict__ pwb,
    const float* __restrict__ pbW, const float* __restrict__ pbb,
    const float* __restrict__ powW, const float* __restrict__ powb,
    const float* __restrict__ pobW, const float* __restrict__ pobb,
    const float* __restrict__ ubW, const float* __restrict__ ubb,
    const float* __restrict__ dbW, const float* __restrict__ dbb,
    float* __restrict__ vecs) {
    int gid = blockIdx.x * 256 + threadIdx.x;
    if (gid >= NB * 2624) return;
    int b = gid / 2624;
    int r = gid - b * 2624;
    const float* W; const float* bias; int off, width;
    if (r < 2560) {
        int v = r >> 9; off = r & 511; width = 512;
        switch (v) {
            case 0:  W = pwW;  bias = pwb;  break;
            case 1:  W = pbW;  bias = pbb;  break;
            case 2:  W = powW; bias = powb; break;
            case 3:  W = pobW; bias = pobb; break;
            default: W = ubW;  bias = ubb;  break;
        }
    } else {
        off = r - 2560; width = 64; W = dbW; bias = dbb;
    }
    float acc = bias[off];
    const float* e = emb + b * 64;
#pragma unroll 8
    for (int k = 0; k < 64; ++k) acc = fmaf(e[k], W[k * width + off], acc);
    vecs[gid] = acc;
}

// ---------------------------------------------------------------------------
// Kernel 1c: fold pre-LN weight into down frags (in place) and compute
// c1'[b,a] = sum_d pre_b[d]*w_down[a,d] + b_down[a],  c2[b,a] = sum_d pre_w[d]*w_down[a,d]
// cvec layout: [b][a][2] interleaved (c1', c2).
// grid: 32 blocks (one per b) x 256 threads (wave = nblk)
// ---------------------------------------------------------------------------
__global__ __launch_bounds__(256) void hyper_c(
    unsigned short* __restrict__ wdfrag,
    const float* __restrict__ vecs,
    float* __restrict__ cvec) {
    const int tid = threadIdx.x;
    const int lane = tid & 63;
    const int nblk = tid >> 6;
    const int lanelo = lane & 15;
    const int quad = lane >> 4;
    const int b = blockIdx.x;
    const float* vb = vecs + b * 2624;
    unsigned short* wdb = wdfrag + (size_t)b * 32768;

    float c1 = 0.f, c2 = 0.f;
#pragma unroll
    for (int kc = 0; kc < 16; ++kc) {
        size_t off = ((size_t)(nblk * 16 + kc) * 64 + lane) * 8;
        uint4 u = *(const uint4*)(wdb + off);
        int d0 = kc * 32 + quad * 8;
        float4 pwA = *(const float4*)(vb + d0);
        float4 pwB = *(const float4*)(vb + d0 + 4);
        float4 pbA = *(const float4*)(vb + 512 + d0);
        float4 pbB = *(const float4*)(vb + 512 + d0 + 4);
        float r0 = bflo(u.x), r1 = bfhi(u.x), r2 = bflo(u.y), r3 = bfhi(u.y);
        float r4 = bflo(u.z), r5 = bfhi(u.z), r6 = bflo(u.w), r7 = bfhi(u.w);
        float f0 = r0 * pwA.x, f1 = r1 * pwA.y, f2 = r2 * pwA.z, f3 = r3 * pwA.w;
        float f4 = r4 * pwB.x, f5 = r5 * pwB.y, f6 = r6 * pwB.z, f7 = r7 * pwB.w;
        c2 += (f0 + f1 + f2 + f3) + (f4 + f5 + f6 + f7);
        c1 += r0 * pbA.x + r1 * pbA.y + r2 * pbA.z + r3 * pbA.w +
              r4 * pbB.x + r5 * pbB.y + r6 * pbB.z + r7 * pbB.w;
        uint4 o;
        o.x = pk(f0, f1); o.y = pk(f2, f3); o.z = pk(f4, f5); o.w = pk(f6, f7);
        *(uint4*)(wdb + off) = o;
    }
    c1 += __shfl_xor(c1, 16); c1 += __shfl_xor(c1, 32);
    c2 += __shfl_xor(c2, 16); c2 += __shfl_xor(c2, 32);
    if (quad == 0) {
        int a = nblk * 16 + lanelo;
        float c1p = c1 + vb[2560 + a];
        cvec[b * 128 + 2 * a] = c1p;
        cvec[b * 128 + 2 * a + 1] = c2;
    }
}

// ---------------------------------------------------------------------------
// Kernel 2: fused  [foldedLN+down MFMA] -> relu -> up(MFMA, 2-pass) -> postLN -> +x
// 2048 blocks x 128 threads; block = (b, 32-row S-tile); wave w = rows 16w..16w+15.
// Waves independent except one early barrier for coeff staging.
// ---------------------------------------------------------------------------
__global__ __launch_bounds__(128, 5) void fused_adapter(
    const float* __restrict__ inp,
    const unsigned short* __restrict__ wdfold,
    const unsigned short* __restrict__ wufrag,
    const float* __restrict__ vecs,
    const float* __restrict__ cvec,
    float* __restrict__ out) {
    __shared__ float coeff[1536];  // post_w[512] post_b[512] b_up[512]
    __shared__ __align__(16) unsigned short mid_lds[2][16][80];

    const int tid = threadIdx.x;
    const int lane = tid & 63;
    const int wave = tid >> 6;
    const int lanelo = lane & 15;
    const int quad = lane >> 4;
    const int bx = blockIdx.x;
    const int b = bx >> 6;
    const int s0 = (bx & 63) * 32;
    const int m0 = wave * 16;

    const float* vb = vecs + b * 2624;
    for (int i = tid; i < 384; i += 128)
        ((float4*)coeff)[i] = ((const float4*)(vb + 1024))[i];
    __syncthreads();

    // ---- merged phase A+B: stream x, stats, bf16 pack, down MFMA ----
    const float* xp = inp + ((size_t)b * NS + s0 + m0 + lanelo) * ND + quad * 8;
    const unsigned short* wd = wdfold + (size_t)b * 32768;
    f32x4 accd[4];
#pragma unroll
    for (int nt = 0; nt < 4; ++nt) accd[nt] = (f32x4){0.f, 0.f, 0.f, 0.f};
    float s = 0.f, q = 0.f;
#pragma unroll
    for (int kc = 0; kc < 16; ++kc) {
        float4 x0 = *(const float4*)(xp + kc * 32);
        float4 x1 = *(const float4*)(xp + kc * 32 + 4);
        s += (x0.x + x0.y + x0.z + x0.w) + (x1.x + x1.y + x1.z + x1.w);
        q = fmaf(x0.x, x0.x, q); q = fmaf(x0.y, x0.y, q);
        q = fmaf(x0.z, x0.z, q); q = fmaf(x0.w, x0.w, q);
        q = fmaf(x1.x, x1.x, q); q = fmaf(x1.y, x1.y, q);
        q = fmaf(x1.z, x1.z, q); q = fmaf(x1.w, x1.w, q);
        uint4 au;
        au.x = pk(x0.x, x0.y); au.y = pk(x0.z, x0.w);
        au.z = pk(x1.x, x1.y); au.w = pk(x1.z, x1.w);
        bf16x8 af = __builtin_bit_cast(bf16x8, au);
#pragma unroll
        for (int nt = 0; nt < 4; ++nt) {
            uint4 bu = *(const uint4*)(wd + ((size_t)(nt * 16 + kc) * 64 + lane) * 8);
            accd[nt] = __builtin_amdgcn_mfma_f32_16x16x32_bf16(
                af, __builtin_bit_cast(bf16x8, bu), accd[nt], 0, 0, 0);
        }
    }
    s += __shfl_xor(s, 16); s += __shfl_xor(s, 32);
    q += __shfl_xor(q, 16); q += __shfl_xor(q, 32);
    float mean = s * (1.0f / 512.0f);
    float var = q * (1.0f / 512.0f) - mean * mean;
    float rstd = rsqrtf(var + 1e-5f);

    // broadcast row stats (row = quad*4+r) into C-layout lanes
    float rs[4], mrs[4];
#pragma unroll
    for (int r = 0; r < 4; ++r) {
        int src = quad * 4 + r;
        rs[r] = __shfl(rstd, src);
        mrs[r] = __shfl(mean, src) * rs[r];
    }

    // down epilogue: down = rs*G + (c1' - mrs*c2); relu; -> mid_lds (A-frag side)
    const float* cv = cvec + b * 128;
#pragma unroll
    for (int nt = 0; nt < 4; ++nt) {
        float2 cc = *(const float2*)(cv + 2 * (nt * 16 + lanelo));
#pragma unroll
        for (int r = 0; r < 4; ++r) {
            float v = fmaf(rs[r], accd[nt][r], fmaf(-mrs[r], cc.y, cc.x));
            v = fmaxf(v, 0.0f);
            mid_lds[wave][quad * 4 + r][nt * 16 + lanelo] = f2bf(v);
        }
    }
    // wave-private transpose readback (no block barrier needed)
    uint4 a0u = *(const uint4*)&mid_lds[wave][lanelo][quad * 8];
    uint4 a1u = *(const uint4*)&mid_lds[wave][lanelo][32 + quad * 8];
    bf16x8 af0 = __builtin_bit_cast(bf16x8, a0u);
    bf16x8 af1 = __builtin_bit_cast(bf16x8, a1u);

    // ---- phase C pass 1: up-GEMM for post-LN stats only ----
    const unsigned short* wu = wufrag + (size_t)b * 32768;
    float sum[4] = {0.f, 0.f, 0.f, 0.f}, sq[4] = {0.f, 0.f, 0.f, 0.f};
#pragma unroll
    for (int nt = 0; nt < 32; ++nt) {
        uint4 b0 = *(const uint4*)(wu + ((size_t)(nt * 2 + 0) * 64 + lane) * 8);
        uint4 b1 = *(const uint4*)(wu + ((size_t)(nt * 2 + 1) * 64 + lane) * 8);
        f32x4 a4 = (f32x4){0.f, 0.f, 0.f, 0.f};
        a4 = __builtin_amdgcn_mfma_f32_16x16x32_bf16(af0, __builtin_bit_cast(bf16x8, b0), a4, 0, 0, 0);
        a4 = __builtin_amdgcn_mfma_f32_16x16x32_bf16(af1, __builtin_bit_cast(bf16x8, b1), a4, 0, 0, 0);
        float bu = coeff[1024 + nt * 16 + lanelo];
#pragma unroll
        for (int r = 0; r < 4; ++r) {
            float y = a4[r] + bu;
            sum[r] += y;
            sq[r] = fmaf(y, y, sq[r]);
        }
    }
#pragma unroll
    for (int r = 0; r < 4; ++r) {
#pragma unroll
        for (int m = 1; m <= 8; m <<= 1) {
            sum[r] += __shfl_xor(sum[r], m);
            sq[r] += __shfl_xor(sq[r], m);
        }
    }
    float mean2[4], rstd2[4];
#pragma unroll
    for (int r = 0; r < 4; ++r) {
        mean2[r] = sum[r] * (1.0f / 512.0f);
        float v2 = sq[r] * (1.0f / 512.0f) - mean2[r] * mean2[r];
        rstd2[r] = rsqrtf(v2 + 1e-5f);
    }

    // ---- phase C pass 2: recompute y, post-LN affine, +x, store ----
    const size_t obase = ((size_t)b * NS + s0 + m0) * ND;
#pragma unroll
    for (int nt = 0; nt < 32; ++nt) {
        uint4 b0 = *(const uint4*)(wu + ((size_t)(nt * 2 + 0) * 64 + lane) * 8);
        uint4 b1 = *(const uint4*)(wu + ((size_t)(nt * 2 + 1) * 64 + lane) * 8);
        f32x4 a4 = (f32x4){0.f, 0.f, 0.f, 0.f};
        a4 = __builtin_amdgcn_mfma_f32_16x16x32_bf16(af0, __builtin_bit_cast(bf16x8, b0), a4, 0, 0, 0);
        a4 = __builtin_amdgcn_mfma_f32_16x16x32_bf16(af1, __builtin_bit_cast(bf16x8, b1), a4, 0, 0, 0);
        int col = nt * 16 + lanelo;
        float bu = coeff[1024 + col];
        float pw = coeff[col];
        float pb = coeff[512 + col];
#pragma unroll
        for (int r = 0; r < 4; ++r) {
            float y = a4[r] + bu;
            size_t off = obase + (size_t)(quad * 4 + r) * ND + col;
            out[off] = fmaf((y - mean2[r]) * rstd2[r], pw, pb) + inp[off];
        }
    }
}

// ---------------------------------------------------------------------------
extern "C" void kernel_launch(void* const* d_in, const int* in_sizes, int n_in,
                              void* d_out, int out_size, void* d_ws, size_t ws_size,
                              hipStream_t stream) {
    const float* emb  = (const float*)d_in[0];
    const float* inp  = (const float*)d_in[1];
    const float* dwW  = (const float*)d_in[2];
    const float* dwb  = (const float*)d_in[3];
    const float* dbW  = (const float*)d_in[4];
    const float* dbb  = (const float*)d_in[5];
    const float* uwW  = (const float*)d_in[6];
    const float* uwb  = (const float*)d_in[7];
    const float* ubW  = (const float*)d_in[8];
    const float* ubb  = (const float*)d_in[9];
    const float* pwW  = (const float*)d_in[10];
    const float* pwb  = (const float*)d_in[11];
    const float* pbW  = (const float*)d_in[12];
    const float* pbb  = (const float*)d_in[13];
    const float* powW = (const float*)d_in[14];
    const float* powb = (const float*)d_in[15];
    const float* pobW = (const float*)d_in[16];
    const float* pobb = (const float*)d_in[17];

    unsigned short* wdfrag = (unsigned short*)d_ws;
    unsigned short* wufrag = wdfrag + (size_t)NB * 32768;
    float* vecs = (float*)(wufrag + (size_t)NB * 32768);
    float* cvec = vecs + (size_t)NB * 2624;

    hyper_pack<<<256, 256, 0, stream>>>(emb, dwW, dwb, uwW, uwb, wdfrag, wufrag);
    hyper_vec<<<(NB * 2624 + 255) / 256, 256, 0, stream>>>(
        emb, pwW, pwb, pbW, pbb, powW, powb, pobW, pobb, ubW, ubb, dbW, dbb, vecs);
    hyper_c<<<NB, 256, 0, stream>>>(wdfrag, vecs, cvec);
    fused_adapter<<<NB * (NS / 32), 128, 0, stream>>>(
        inp, wdfrag, wufrag, vecs, cvec, (float*)d_out);
}

// Round 3
// 330.236 us; speedup vs baseline: 1.3004x; 1.3004x over previous
//
#include <hip/hip_runtime.h>

#define NB 32
#define NS 2048
#define ND 512
#define NA 64
#define NE 64

typedef __bf16 bf16x8 __attribute__((ext_vector_type(8)));
typedef float f32x4 __attribute__((ext_vector_type(4)));

__device__ __forceinline__ unsigned short f2bf(float f) {
    union { float f; unsigned u; } v; v.f = f;
    unsigned r = (v.u + 0x7fffu + ((v.u >> 16) & 1u)) >> 16;
    return (unsigned short)r;
}
__device__ __forceinline__ unsigned pk(float a, float b) {
    return (unsigned)f2bf(a) | ((unsigned)f2bf(b) << 16);
}

// ---------------------------------------------------------------------------
// Kernel 1b (runs FIRST): the six small per-sample vectors, per b:
// [pre_w 512][pre_b 512][post_w 512][post_b 512][b_up 512][b_down 64] = 2624
// ---------------------------------------------------------------------------
__global__ __launch_bounds__(256) void hyper_vec(
    const float* __restrict__ emb,
    const float* __restrict__ pwW, const float* __restrict__ pwb,
    const float* __restrict__ pbW, const float* __restrict__ pbb,
    const float* __restrict__ powW, const float* __restrict__ powb,
    const float* __restrict__ pobW, const float* __restrict__ pobb,
    const float* __restrict__ ubW, const float* __restrict__ ubb,
    const float* __restrict__ dbW, const float* __restrict__ dbb,
    float* __restrict__ vecs) {
    int gid = blockIdx.x * 256 + threadIdx.x;
    if (gid >= NB * 2624) return;
    int b = gid / 2624;
    int r = gid - b * 2624;
    const float* W; const float* bias; int off, width;
    if (r < 2560) {
        int v = r >> 9; off = r & 511; width = 512;
        switch (v) {
            case 0:  W = pwW;  bias = pwb;  break;
            case 1:  W = pbW;  bias = pbb;  break;
            case 2:  W = powW; bias = powb; break;
            case 3:  W = pobW; bias = pobb; break;
            default: W = ubW;  bias = ubb;  break;
        }
    } else {
        off = r - 2560; width = 64; W = dbW; bias = dbb;
    }
    float acc = bias[off];
    const float* e = emb + b * 64;
#pragma unroll 8
    for (int k = 0; k < 64; ++k) acc = fmaf(e[k], W[k * width + off], acc);
    vecs[gid] = acc;
}

// ---------------------------------------------------------------------------
// Kernel 1a: hypernet big GEMMs emb[32,64] @ W[64,32768] -> bf16 frags.
// mat==0 (down): fold pre-LN weight in-line (f = raw*pre_w), emit folded
//   frags [b][nt(4)][kc(16)][lane(64)][8] and atomically accumulate
//   c1[b,a]=sum_d raw*pre_b, c2[b,a]=sum_d raw*pre_w into cvec[b][a][2].
// mat==1 (up): frags [b][nblk(32)][kch(2)][lane(64)][8].
// grid: 512 blocks (mat 0/1 x 256 col-chunks of 128), 256 threads.
// Thread t: col = base + (t&127), b-half = t>>7 (16 b's each).
// ---------------------------------------------------------------------------
__global__ __launch_bounds__(256) void hyper_pack(
    const float* __restrict__ emb,
    const float* __restrict__ dwW, const float* __restrict__ dwb,
    const float* __restrict__ uwW, const float* __restrict__ uwb,
    const float* __restrict__ vecs,
    unsigned short* __restrict__ wdfrag, unsigned short* __restrict__ wufrag,
    float* __restrict__ cvec) {
    __shared__ float Wt[64][128];
    __shared__ float embs[NB * NE];
    const int tid = threadIdx.x;
    const int lane = tid & 63;
    const int bx = blockIdx.x;
    const int mat = bx >> 8;
    const int chunk = bx & 255;
    const int base = chunk * 128;
    const int colo = tid & 127;
    const int bh = tid >> 7;            // 0 or 1: b-range [16*bh, 16*bh+16)
    const float* W = mat ? uwW : dwW;
    const float* bias = mat ? uwb : dwb;

    for (int i = tid; i < NB * NE; i += 256) embs[i] = emb[i];
    for (int i = tid; i < 64 * 32; i += 256) {
        int k = i >> 5, c = (i & 31) << 2;
        *(float4*)&Wt[k][c] = *(const float4*)&W[(size_t)k * 32768 + base + c];
    }
    __syncthreads();

    const int col = base + colo;
    const float bv = bias[col];
    float acc[16];
#pragma unroll
    for (int b = 0; b < 16; ++b) acc[b] = bv;

    for (int k0 = 0; k0 < 64; k0 += 4) {
        float w0 = Wt[k0][colo], w1 = Wt[k0 + 1][colo];
        float w2 = Wt[k0 + 2][colo], w3 = Wt[k0 + 3][colo];
#pragma unroll
        for (int b = 0; b < 16; ++b) {
            float4 e = *(const float4*)&embs[(bh * 16 + b) * 64 + k0];
            acc[b] = fmaf(e.x, w0, acc[b]);
            acc[b] = fmaf(e.y, w1, acc[b]);
            acc[b] = fmaf(e.z, w2, acc[b]);
            acc[b] = fmaf(e.w, w3, acc[b]);
        }
    }

    if (mat == 0) {
        int a = col >> 9, d = col & 511;   // a uniform per block (128 | 512)
        size_t idx0 = ((size_t)((a >> 4) * 16 + (d >> 5)) * 64 +
                       (((d & 31) >> 3) * 16 + (a & 15))) * 8 + (d & 7);
#pragma unroll
        for (int b = 0; b < 16; ++b) {
            int bg = bh * 16 + b;
            float raw = acc[b];
            float pw = vecs[bg * 2624 + d];
            float pb = vecs[bg * 2624 + 512 + d];
            float f = raw * pw;
            wdfrag[idx0 + (size_t)bg * 32768] = f2bf(f);
            float c2v = f, c1v = raw * pb;
#pragma unroll
            for (int m = 1; m <= 32; m <<= 1) {
                c2v += __shfl_xor(c2v, m);
                c1v += __shfl_xor(c1v, m);
            }
            if (lane == 0) {
                atomicAdd(&cvec[bg * 128 + 2 * a], c1v);
                atomicAdd(&cvec[bg * 128 + 2 * a + 1], c2v);
            }
        }
    } else {
        int d = col >> 6, a = col & 63;
        size_t idx0 = ((size_t)((d >> 4) * 2 + (a >> 5)) * 64 +
                       (((a & 31) >> 3) * 16 + (d & 15))) * 8 + (a & 7);
#pragma unroll
        for (int b = 0; b < 16; ++b)
            wufrag[idx0 + (size_t)(bh * 16 + b) * 32768] = f2bf(acc[b]);
    }
}

// ---------------------------------------------------------------------------
// Kernel 2: fused [foldedLN + down MFMA] -> relu -> up (MFMA, col-split) ->
// postLN -> +x.  4096 blocks x 256 threads; block = (b, 16-row S-tile).
// Wave w: loads K-quarter [128w,128w+128) of x; down nt=w; up cols
// [128w,128w+128) with acc[8]. Stats combined via small LDS arrays.
// ---------------------------------------------------------------------------
__global__ __launch_bounds__(256, 5) void fused_adapter(
    const float* __restrict__ inp,
    const unsigned short* __restrict__ wdfold,
    const unsigned short* __restrict__ wufrag,
    const float* __restrict__ vecs,
    const float* __restrict__ cvec,
    float* __restrict__ out) {
    __shared__ __align__(16) unsigned short z_lds[16][520];
    __shared__ __align__(16) unsigned short mid_lds[16][72];
    __shared__ __align__(16) float coeff[1536];  // post_w | post_b | b_up
    __shared__ __align__(16) float preS[16][4], preQ[16][4];
    __shared__ __align__(16) float postS[16][4], postQ[16][4];

    const int tid = threadIdx.x;
    const int lane = tid & 63;
    const int wave = tid >> 6;
    const int lanelo = lane & 15;
    const int quad = lane >> 4;
    const int bx = blockIdx.x;
    const int b = bx >> 7;
    const int s0 = (bx & 127) * 16;

    const float* vb = vecs + b * 2624;
    for (int i = tid; i < 384; i += 256)
        ((float4*)coeff)[i] = ((const float4*)(vb + 1024))[i];

    // ---- Phase A: wave w loads cols [128w,128w+128) of the 16 rows ----
    const float* xp = inp + ((size_t)b * NS + s0 + lanelo) * ND + wave * 128 + quad * 8;
    float s = 0.f, q = 0.f;
#pragma unroll
    for (int kc2 = 0; kc2 < 4; ++kc2) {
        float4 x0 = *(const float4*)(xp + kc2 * 32);
        float4 x1 = *(const float4*)(xp + kc2 * 32 + 4);
        s += (x0.x + x0.y + x0.z + x0.w) + (x1.x + x1.y + x1.z + x1.w);
        q = fmaf(x0.x, x0.x, q); q = fmaf(x0.y, x0.y, q);
        q = fmaf(x0.z, x0.z, q); q = fmaf(x0.w, x0.w, q);
        q = fmaf(x1.x, x1.x, q); q = fmaf(x1.y, x1.y, q);
        q = fmaf(x1.z, x1.z, q); q = fmaf(x1.w, x1.w, q);
        uint4 au;
        au.x = pk(x0.x, x0.y); au.y = pk(x0.z, x0.w);
        au.z = pk(x1.x, x1.y); au.w = pk(x1.z, x1.w);
        *(uint4*)&z_lds[lanelo][wave * 128 + kc2 * 32 + quad * 8] = au;
    }
    s += __shfl_xor(s, 16); s += __shfl_xor(s, 32);
    q += __shfl_xor(q, 16); q += __shfl_xor(q, 32);
    if (lane < 16) { preS[lane][wave] = s; preQ[lane][wave] = q; }
    __syncthreads();  // z + pre-stat partials + coeff visible

    float rs[4], mrs[4];
#pragma unroll
    for (int r = 0; r < 4; ++r) {
        int row = quad * 4 + r;
        float4 S = *(const float4*)preS[row];
        float4 Q = *(const float4*)preQ[row];
        float ss = (S.x + S.y) + (S.z + S.w);
        float qq = (Q.x + Q.y) + (Q.z + Q.w);
        float mean = ss * (1.0f / 512.0f);
        float var = qq * (1.0f / 512.0f) - mean * mean;
        float rstd = rsqrtf(var + 1e-5f);
        rs[r] = rstd;
        mrs[r] = mean * rstd;
    }

    // ---- Phase B: down GEMM, nt = wave; acc is one f32x4 ----
    const unsigned short* wd = wdfold + (size_t)b * 32768;
    f32x4 accd = (f32x4){0.f, 0.f, 0.f, 0.f};
#pragma unroll
    for (int kc = 0; kc < 16; ++kc) {
        uint4 au = *(const uint4*)&z_lds[lanelo][kc * 32 + quad * 8];
        uint4 bu = *(const uint4*)(wd + ((size_t)(wave * 16 + kc) * 64 + lane) * 8);
        accd = __builtin_amdgcn_mfma_f32_16x16x32_bf16(
            __builtin_bit_cast(bf16x8, au), __builtin_bit_cast(bf16x8, bu), accd, 0, 0, 0);
    }
    const int a_col = wave * 16 + lanelo;
    float2 cc = *(const float2*)(cvec + b * 128 + 2 * a_col);
    float c1 = cc.x + vb[2560 + a_col];
#pragma unroll
    for (int r = 0; r < 4; ++r) {
        float v = fmaf(rs[r], accd[r], fmaf(-mrs[r], cc.y, c1));
        mid_lds[quad * 4 + r][a_col] = f2bf(fmaxf(v, 0.0f));
    }
    __syncthreads();  // mid visible

    // ---- Phase C: up GEMM, wave w -> cols [128w,128w+128), acc[8] ----
    uint4 a0u = *(const uint4*)&mid_lds[lanelo][quad * 8];
    uint4 a1u = *(const uint4*)&mid_lds[lanelo][32 + quad * 8];
    bf16x8 af0 = __builtin_bit_cast(bf16x8, a0u);
    bf16x8 af1 = __builtin_bit_cast(bf16x8, a1u);
    const unsigned short* wu = wufrag + (size_t)b * 32768;
    f32x4 acc8[8];
    float sum[4] = {0.f, 0.f, 0.f, 0.f}, sq[4] = {0.f, 0.f, 0.f, 0.f};
#pragma unroll
    for (int nt8 = 0; nt8 < 8; ++nt8) {
        int nt = wave * 8 + nt8;
        uint4 b0 = *(const uint4*)(wu + ((size_t)(nt * 2 + 0) * 64 + lane) * 8);
        uint4 b1 = *(const uint4*)(wu + ((size_t)(nt * 2 + 1) * 64 + lane) * 8);
        f32x4 a4 = (f32x4){0.f, 0.f, 0.f, 0.f};
        a4 = __builtin_amdgcn_mfma_f32_16x16x32_bf16(af0, __builtin_bit_cast(bf16x8, b0), a4, 0, 0, 0);
        a4 = __builtin_amdgcn_mfma_f32_16x16x32_bf16(af1, __builtin_bit_cast(bf16x8, b1), a4, 0, 0, 0);
        float bu = coeff[1024 + nt * 16 + lanelo];
#pragma unroll
        for (int r = 0; r < 4; ++r) {
            float y = a4[r] + bu;
            a4[r] = y;
            sum[r] += y;
            sq[r] = fmaf(y, y, sq[r]);
        }
        acc8[nt8] = a4;
    }
#pragma unroll
    for (int r = 0; r < 4; ++r) {
#pragma unroll
        for (int m = 1; m <= 8; m <<= 1) {
            sum[r] += __shfl_xor(sum[r], m);
            sq[r] += __shfl_xor(sq[r], m);
        }
    }
    if (lanelo == 0) {
#pragma unroll
        for (int r = 0; r < 4; ++r) {
            postS[quad * 4 + r][wave] = sum[r];
            postQ[quad * 4 + r][wave] = sq[r];
        }
    }
    __syncthreads();  // post-stat partials visible

    float mean2[4], rstd2[4];
#pragma unroll
    for (int r = 0; r < 4; ++r) {
        int row = quad * 4 + r;
        float4 S = *(const float4*)postS[row];
        float4 Q = *(const float4*)postQ[row];
        float ss = (S.x + S.y) + (S.z + S.w);
        float qq = (Q.x + Q.y) + (Q.z + Q.w);
        mean2[r] = ss * (1.0f / 512.0f);
        float v2 = qq * (1.0f / 512.0f) - mean2[r] * mean2[r];
        rstd2[r] = rsqrtf(v2 + 1e-5f);
    }

    // ---- epilogue: post-LN affine, +x, store ----
    const size_t obase = ((size_t)b * NS + s0) * ND;
#pragma unroll
    for (int nt8 = 0; nt8 < 8; ++nt8) {
        int col = (wave * 8 + nt8) * 16 + lanelo;
        float pw = coeff[col];
        float pb = coeff[512 + col];
#pragma unroll
        for (int r = 0; r < 4; ++r) {
            size_t off = obase + (size_t)(quad * 4 + r) * ND + col;
            out[off] = fmaf((acc8[nt8][r] - mean2[r]) * rstd2[r], pw, pb) + inp[off];
        }
    }
}

// ---------------------------------------------------------------------------
extern "C" void kernel_launch(void* const* d_in, const int* in_sizes, int n_in,
                              void* d_out, int out_size, void* d_ws, size_t ws_size,
                              hipStream_t stream) {
    const float* emb  = (const float*)d_in[0];
    const float* inp  = (const float*)d_in[1];
    const float* dwW  = (const float*)d_in[2];
    const float* dwb  = (const float*)d_in[3];
    const float* dbW  = (const float*)d_in[4];
    const float* dbb  = (const float*)d_in[5];
    const float* uwW  = (const float*)d_in[6];
    const float* uwb  = (const float*)d_in[7];
    const float* ubW  = (const float*)d_in[8];
    const float* ubb  = (const float*)d_in[9];
    const float* pwW  = (const float*)d_in[10];
    const float* pwb  = (const float*)d_in[11];
    const float* pbW  = (const float*)d_in[12];
    const float* pbb  = (const float*)d_in[13];
    const float* powW = (const float*)d_in[14];
    const float* powb = (const float*)d_in[15];
    const float* pobW = (const float*)d_in[16];
    const float* pobb = (const float*)d_in[17];

    unsigned short* wdfrag = (unsigned short*)d_ws;
    unsigned short* wufrag = wdfrag + (size_t)NB * 32768;
    float* vecs = (float*)(wufrag + (size_t)NB * 32768);
    float* cvec = vecs + (size_t)NB * 2624;

    hyper_vec<<<(NB * 2624 + 255) / 256, 256, 0, stream>>>(
        emb, pwW, pwb, pbW, pbb, powW, powb, pobW, pobb, ubW, ubb, dbW, dbb, vecs);
    hipMemsetAsync(cvec, 0, (size_t)NB * 128 * sizeof(float), stream);
    hyper_pack<<<512, 256, 0, stream>>>(emb, dwW, dwb, uwW, uwb, vecs,
                                        wdfrag, wufrag, cvec);
    fused_adapter<<<NB * (NS / 16), 256, 0, stream>>>(
        inp, wdfrag, wufrag, vecs, cvec, (float*)d_out);
}